// Round 7
// baseline (727.424 us; speedup 1.0000x reference)
//
#include <hip/hip_runtime.h>

#define D_FEAT 128
typedef unsigned int u32;
typedef u32   u32x4 __attribute__((ext_vector_type(4)));
typedef float f32x4 __attribute__((ext_vector_type(4)));

__device__ __forceinline__ float bflo(u32 w) {
    u32 b = w << 16;
    return __builtin_bit_cast(float, b);
}
__device__ __forceinline__ float bfhi(u32 w) {
    u32 b = w & 0xFFFF0000u;
    return __builtin_bit_cast(float, b);
}
__device__ __forceinline__ u32 f2bf(float f) {
    u32 x = __builtin_bit_cast(u32, f);
    return (x + 0x7FFFu + ((x >> 16) & 1u)) >> 16;
}
__device__ __forceinline__ u32 pack2(float lo, float hi) {
    return f2bf(lo) | (f2bf(hi) << 16);
}

// ---------------- CSR build helpers ----------------

__global__ void hist_keys(const int* __restrict__ key, int* __restrict__ deg, int n) {
    int e = blockIdx.x * blockDim.x + threadIdx.x;
    if (e < n) atomicAdd(&deg[__builtin_nontemporal_load(&key[e])], 1);
}

__global__ void scan_blocks(const int* __restrict__ deg, int* __restrict__ ptrOut,
                            int* __restrict__ bsum, int n) {
    __shared__ int s[256];
    int t = threadIdx.x;
    int i = blockIdx.x * 256 + t;
    int v = (i < n) ? deg[i] : 0;
    s[t] = v;
    __syncthreads();
    for (int off = 1; off < 256; off <<= 1) {
        int add = (t >= off) ? s[t - off] : 0;
        __syncthreads();
        s[t] += add;
        __syncthreads();
    }
    if (i < n) ptrOut[i] = s[t] - v;
    if (t == 255) bsum[blockIdx.x] = s[255];
}

__global__ void scan_bsums(int* __restrict__ bsum, int nb) {
    __shared__ int s[1024];
    int t = threadIdx.x;
    int v = (t < nb) ? bsum[t] : 0;
    s[t] = v;
    __syncthreads();
    for (int off = 1; off < 1024; off <<= 1) {
        int add = (t >= off) ? s[t - off] : 0;
        __syncthreads();
        s[t] += add;
        __syncthreads();
    }
    if (t < nb) bsum[t] = s[t] - v;
}

__global__ void add_offsets(int* __restrict__ ptr, int* __restrict__ next,
                            const int* __restrict__ bsum, int n, int total) {
    int i = blockIdx.x * blockDim.x + threadIdx.x;
    if (i < n) {
        int p = ptr[i] + bsum[i >> 8];
        ptr[i] = p;
        next[i] = p;
    }
    if (i == n) ptr[n] = total;
}

// ---- Phase A: single-pass partition of edges into 8 staged buckets + deg hist ----
// Each block handles 4096 edges (16/thread). Per-bucket block-local prefix via LDS,
// one global cursor atomicAdd per bucket per block, packed (r_local<<cbits)|col writes.
__global__ void partition_edges(const int* __restrict__ row, const int* __restrict__ col,
                                int* __restrict__ deg, u32* __restrict__ cursor,
                                u32* __restrict__ stag, int nE, int W,
                                unsigned long long M, int cbits, int capB) {
    __shared__ int ms[256][9];
    __shared__ int s[256];
    __shared__ int bBase[8];
    int t = threadIdx.x;
    long long base = (long long)blockIdx.x * 4096;
    int r[16];
#pragma unroll
    for (int b = 0; b < 8; ++b) ms[t][b] = 0;
#pragma unroll
    for (int k = 0; k < 16; ++k) {
        long long e = base + k * 256 + t;
        int rv = -1;
        if (e < nE) rv = __builtin_nontemporal_load(&row[e]);
        r[k] = rv;
        if (rv >= 0) {
            atomicAdd(&deg[rv], 1);
            int b = (int)(((unsigned long long)(u32)rv * M) >> 40);
            ms[t][b]++;
        }
    }
#pragma unroll
    for (int b = 0; b < 8; ++b) {
        __syncthreads();
        s[t] = ms[t][b];
        __syncthreads();
        for (int off = 1; off < 256; off <<= 1) {
            int add = (t >= off) ? s[t - off] : 0;
            __syncthreads();
            s[t] += add;
            __syncthreads();
        }
        int incl = s[t];
        int vcnt = ms[t][b];
        if (t == 255) bBase[b] = (int)atomicAdd(&cursor[b], (u32)incl);
        ms[t][b] = incl - vcnt;   // exclusive within-block prefix
    }
    __syncthreads();
#pragma unroll
    for (int k = 0; k < 16; ++k) {
        int rv = r[k];
        if (rv >= 0) {
            long long e = base + k * 256 + t;
            int c = __builtin_nontemporal_load(&col[e]);
            int b = (int)(((unsigned long long)(u32)rv * M) >> 40);
            int dst = bBase[b] + ms[t][b]++;
            if (dst < capB)
                stag[(size_t)b * capB + dst] = ((u32)(rv - b * W) << cbits) | (u32)c;
        }
    }
}

// ---- Phase B: per-bucket atomic placement into its colS window (XCD affinity) ----
__global__ void scatter_staged(const u32* __restrict__ cursor, const u32* __restrict__ stag,
                               int* __restrict__ next, int* __restrict__ colS,
                               int W, int cbits, int capB) {
    int b = blockIdx.x & 7;
    int nchunk = gridDim.x >> 3;
    int chunk = blockIdx.x >> 3;
    int cnt = (int)cursor[b];
    if (cnt > capB) cnt = capB;
    int lo = b * W;
    u32 cmask = (1u << cbits) - 1;
    const u32* sb = stag + (size_t)b * capB;
    for (int i = chunk * 256 + threadIdx.x; i < cnt; i += nchunk * 256) {
        u32 w = __builtin_nontemporal_load(&sb[i]);
        int r = lo + (int)(w >> cbits);
        int c = (int)(w & cmask);
        int pos = atomicAdd(&next[r], 1);
        colS[pos] = c;
    }
}

// ---- old one-pass bucketed scatter (fallback when staging doesn't fit) ----
#define EPB 2048
__global__ void scatter_cols_b(const int* __restrict__ row, const int* __restrict__ col,
                               int* __restrict__ next, int* __restrict__ colS,
                               int nE, int W) {
    int bucket = blockIdx.x & 7;
    int chunk  = blockIdx.x >> 3;
    int lo = bucket * W;
    int base = chunk * EPB;
    for (int k = threadIdx.x; k < EPB; k += 256) {
        int e = base + k;
        if (e < nE) {
            int r = __builtin_nontemporal_load(&row[e]);
            if ((unsigned)(r - lo) < (unsigned)W) {
                int c = __builtin_nontemporal_load(&col[e]);
                int pos = atomicAdd(&next[r], 1);
                colS[pos] = c;
            }
        }
    }
}

__global__ void scatter_iota(const int* __restrict__ idx, int* __restrict__ inext,
                             int* __restrict__ idxS, int n) {
    int j = blockIdx.x * blockDim.x + threadIdx.x;
    if (j < n) {
        int pos = atomicAdd(&inext[__builtin_nontemporal_load(&idx[j])], 1);
        idxS[pos] = j;
    }
}

// h0(bf16)[n] = x[n] + sum x_id[idxS[...]]  — 2 nodes/wave, 32 lanes/node
__global__ void init_plus_gather_bf(const int* __restrict__ iptr, const int* __restrict__ idxS,
                                    const float4* __restrict__ x, const float4* __restrict__ x_id,
                                    uint2* __restrict__ h, int n) {
    size_t tid = blockIdx.x * (size_t)blockDim.x + threadIdx.x;
    int wv   = (int)(tid >> 6);
    int lane = threadIdx.x & 63;
    int node = wv * 2 + (lane >> 5);
    int q    = lane & 31;
    if (node >= n) return;
    float4 a = x[(size_t)node * 32 + q];
    int e = iptr[node], end = iptr[node + 1];
    for (; e < end; ++e) {
        float4 v = x_id[(size_t)idxS[e] * 32 + q];
        a.x += v.x; a.y += v.y; a.z += v.z; a.w += v.w;
    }
    uint2 w;
    w.x = pack2(a.x, a.y);
    w.y = pack2(a.z, a.w);
    h[(size_t)node * 32 + q] = w;
}

// ---------------- hops: one wave per node, 16-edge main loop (4 row-loads in flight) ----

#define ACC(A0,A1,A2,A3,A4,A5,A6,A7,V)                                                \
    A0 += bflo(V.x); A1 += bfhi(V.x); A2 += bflo(V.y); A3 += bfhi(V.y);               \
    A4 += bflo(V.z); A5 += bfhi(V.z); A6 += bflo(V.w); A7 += bfhi(V.w);

#define GATHER_BODY                                                                   \
    int wv = (int)((blockIdx.x * (size_t)blockDim.x + threadIdx.x) >> 6);             \
    if (wv >= n) return;                                                              \
    int lane = threadIdx.x & 63;                                                      \
    int g = lane >> 4;                                                                \
    int q = lane & 15;                                                                \
    int beg = ptr[wv], end = ptr[wv + 1];                                             \
    float a0 = 0, a1 = 0, a2 = 0, a3 = 0, a4 = 0, a5 = 0, a6 = 0, a7 = 0;             \
    float b0 = 0, b1 = 0, b2 = 0, b3 = 0, b4 = 0, b5 = 0, b6 = 0, b7 = 0;             \
    int e = beg;                                                                      \
    for (; e + 16 <= end; e += 16) {                                                  \
        int c0 = __builtin_nontemporal_load(&colS[e + g]);                            \
        int c1 = __builtin_nontemporal_load(&colS[e + 4 + g]);                        \
        int c2 = __builtin_nontemporal_load(&colS[e + 8 + g]);                        \
        int c3 = __builtin_nontemporal_load(&colS[e + 12 + g]);                       \
        uint4 v0 = h[(size_t)c0 * 16 + q];                                            \
        uint4 v1 = h[(size_t)c1 * 16 + q];                                            \
        uint4 v2 = h[(size_t)c2 * 16 + q];                                            \
        uint4 v3 = h[(size_t)c3 * 16 + q];                                            \
        ACC(a0,a1,a2,a3,a4,a5,a6,a7, v0)                                              \
        ACC(b0,b1,b2,b3,b4,b5,b6,b7, v1)                                              \
        ACC(a0,a1,a2,a3,a4,a5,a6,a7, v2)                                              \
        ACC(b0,b1,b2,b3,b4,b5,b6,b7, v3)                                              \
    }                                                                                 \
    for (; e < end; e += 4) {                                                         \
        int ce = e + g;                                                               \
        if (ce < end) {                                                               \
            int c = __builtin_nontemporal_load(&colS[ce]);                            \
            uint4 v = h[(size_t)c * 16 + q];                                          \
            ACC(a0,a1,a2,a3,a4,a5,a6,a7, v)                                           \
        }                                                                             \
    }                                                                                 \
    a0 += b0; a1 += b1; a2 += b2; a3 += b3;                                           \
    a4 += b4; a5 += b5; a6 += b6; a7 += b7;                                           \
    a0 += __shfl_xor(a0, 16, 64); a0 += __shfl_xor(a0, 32, 64);                       \
    a1 += __shfl_xor(a1, 16, 64); a1 += __shfl_xor(a1, 32, 64);                       \
    a2 += __shfl_xor(a2, 16, 64); a2 += __shfl_xor(a2, 32, 64);                       \
    a3 += __shfl_xor(a3, 16, 64); a3 += __shfl_xor(a3, 32, 64);                       \
    a4 += __shfl_xor(a4, 16, 64); a4 += __shfl_xor(a4, 32, 64);                       \
    a5 += __shfl_xor(a5, 16, 64); a5 += __shfl_xor(a5, 32, 64);                       \
    a6 += __shfl_xor(a6, 16, 64); a6 += __shfl_xor(a6, 32, 64);                       \
    a7 += __shfl_xor(a7, 16, 64); a7 += __shfl_xor(a7, 32, 64);

__global__ void gather_node_bf_bf(const int* __restrict__ ptr, const int* __restrict__ colS,
                                  const uint4* __restrict__ h, u32* __restrict__ out, int n) {
    GATHER_BODY
    if (g == 0) {
        u32x4 w;
        w.x = pack2(a0, a1);
        w.y = pack2(a2, a3);
        w.z = pack2(a4, a5);
        w.w = pack2(a6, a7);
        __builtin_nontemporal_store(w, (u32x4*)(out + (size_t)wv * 64 + q * 4));
    }
}

__global__ void gather_node_bf_f32(const int* __restrict__ ptr, const int* __restrict__ colS,
                                   const uint4* __restrict__ h, float* __restrict__ out, int n) {
    GATHER_BODY
    if (g == 0) {
        f32x4 w = {a0, a1, a2, a3};
        __builtin_nontemporal_store(w, (f32x4*)(out + (size_t)wv * 128 + q * 8));
    } else if (g == 1) {
        f32x4 w = {a4, a5, a6, a7};
        __builtin_nontemporal_store(w, (f32x4*)(out + (size_t)wv * 128 + q * 8 + 4));
    }
}

// ---------------- fallback kernels (atomic fp32 path) ----------------

__global__ void init_h0(const float4* __restrict__ x, float4* __restrict__ h, int n4) {
    int i = blockIdx.x * blockDim.x + threadIdx.x;
    if (i < n4) h[i] = x[i];
}

__global__ void scatter_id(const float4* __restrict__ x_id, const int* __restrict__ idx,
                           float* __restrict__ h, int n) {
    int t = blockIdx.x * blockDim.x + threadIdx.x;
    int r = t >> 5;
    int q = t & 31;
    if (r < n) {
        float4 v = x_id[r * 32 + q];
        float* o = h + (size_t)idx[r] * D_FEAT + q * 4;
        atomicAdd(o + 0, v.x);
        atomicAdd(o + 1, v.y);
        atomicAdd(o + 2, v.z);
        atomicAdd(o + 3, v.w);
    }
}

__global__ void edge_scatter(const int* __restrict__ row, const int* __restrict__ col,
                             const float4* __restrict__ h, float* __restrict__ out, int nE) {
    int t = blockIdx.x * blockDim.x + threadIdx.x;
    int e = t >> 5;
    int q = t & 31;
    if (e < nE) {
        float4 v = h[col[e] * 32 + q];
        float* o = out + (size_t)row[e] * D_FEAT + q * 4;
        atomicAdd(o + 0, v.x);
        atomicAdd(o + 1, v.y);
        atomicAdd(o + 2, v.z);
        atomicAdd(o + 3, v.w);
    }
}

extern "C" void kernel_launch(void* const* d_in, const int* in_sizes, int n_in,
                              void* d_out, int out_size, void* d_ws, size_t ws_size,
                              hipStream_t stream) {
    const float* x    = (const float*)d_in[0];
    const float* x_id = (const float*)d_in[1];
    const int*   edge = (const int*)d_in[2];   // [2, nE]: row then col
    const int*   idx  = (const int*)d_in[3];

    int nE = in_sizes[2] / 2;
    int nN = in_sizes[3];
    const int* row = edge;
    const int* col = edge + nE;

    float* out = (float*)d_out;
    size_t hbytes  = (size_t)nN * D_FEAT * sizeof(float);
    size_t hbbytes = (size_t)nN * D_FEAT * 2;
    int NB = (nN + 255) / 256;
    int W  = (nN + 7) / 8;

    // ---- workspace layout ----
    char* base = (char*)d_ws;
    uint4* hb0  = (uint4*)base;                            // hbbytes
    uint4* hb1  = (uint4*)(base + hbbytes);                // hbbytes
    int*   ptr   = (int*)(base + 2 * hbbytes);             // nN+1
    int*   next  = ptr + (nN + 1);                         // nN
    int*   bsum  = next + nN;                              // NB (padded)
    int*   colS  = bsum + ((NB + 3) & ~3);                 // nE
    int*   iptr  = colS + nE;                              // nN+1
    int*   inext = iptr + (nN + 1);                        // nN
    int*   ibsum = inext + nN;                             // NB (padded)
    int*   idxS  = ibsum + ((NB + 3) & ~3);                // nN
    u32*   cursor = (u32*)(idxS + nN);                     // 8 (pad 16)
    u32*   stag   = cursor + 16;                           // 8*capB
    int    capB   = nE / 8 + 65536;
    size_t needBF = 2 * hbbytes + sizeof(int) *
        ((size_t)(nN + 1) * 2 + (size_t)nN * 2 + 2 * ((NB + 3) & ~3) + nE + nN);
    size_t needST = needBF + sizeof(u32) * (16 + (size_t)capB * 8);

    int cbits = 0;
    while ((1 << cbits) < nN && cbits < 30) cbits++;
    int rbits = 0;
    while ((1 << rbits) < W && rbits < 30) rbits++;
    bool canPack = (cbits + rbits <= 32) && (W >= 2048);

    int n4 = nN * D_FEAT / 4;
    unsigned int gEdge = (nE + 255) / 256;
    unsigned int gNode = (nN + 255) / 256;

    if (needBF > ws_size || NB > 1024) {
        float* h = (float*)d_ws;
        (void)hipMemsetAsync(out, 0, hbytes, stream);
        hipLaunchKernelGGL(init_h0, dim3((n4 + 255) / 256), dim3(256), 0, stream,
                           (const float4*)x, (float4*)h, n4);
        hipLaunchKernelGGL(scatter_id, dim3((nN * 32 + 255) / 256), dim3(256), 0, stream,
                           (const float4*)x_id, idx, h, nN);
        long long totE = (long long)nE * 32;
        unsigned int gE = (unsigned int)((totE + 255) / 256);
        hipLaunchKernelGGL(edge_scatter, dim3(gE), dim3(256), 0, stream,
                           row, col, (const float4*)h, out, nE);
        (void)hipMemsetAsync(h, 0, hbytes, stream);
        hipLaunchKernelGGL(edge_scatter, dim3(gE), dim3(256), 0, stream,
                           row, col, (const float4*)out, h, nE);
        (void)hipMemsetAsync(out, 0, hbytes, stream);
        hipLaunchKernelGGL(edge_scatter, dim3(gE), dim3(256), 0, stream,
                           row, col, (const float4*)h, out, nE);
        return;
    }

    bool useStaged = canPack && (needST <= ws_size);

    // ---- edge CSR build ----
    (void)hipMemsetAsync(next, 0, (size_t)nN * sizeof(int), stream);
    if (useStaged) {
        (void)hipMemsetAsync(cursor, 0, 16 * sizeof(u32), stream);
        unsigned long long M = ((1ULL << 40) + W - 1) / (unsigned long long)W;
        unsigned int PB = (unsigned int)((nE + 4095) / 4096);
        hipLaunchKernelGGL(partition_edges, dim3(PB), dim3(256), 0, stream,
                           row, col, next, cursor, stag, nE, W, M, cbits, capB);
        hipLaunchKernelGGL(scan_blocks, dim3(NB), dim3(256), 0, stream, next, ptr, bsum, nN);
        hipLaunchKernelGGL(scan_bsums, dim3(1), dim3(1024), 0, stream, bsum, NB);
        hipLaunchKernelGGL(add_offsets, dim3((nN + 1 + 255) / 256), dim3(256), 0, stream,
                           ptr, next, bsum, nN, nE);
        hipLaunchKernelGGL(scatter_staged, dim3(512), dim3(256), 0, stream,
                           cursor, stag, next, colS, W, cbits, capB);
    } else {
        hipLaunchKernelGGL(hist_keys, dim3(gEdge), dim3(256), 0, stream, row, next, nE);
        hipLaunchKernelGGL(scan_blocks, dim3(NB), dim3(256), 0, stream, next, ptr, bsum, nN);
        hipLaunchKernelGGL(scan_bsums, dim3(1), dim3(1024), 0, stream, bsum, NB);
        hipLaunchKernelGGL(add_offsets, dim3((nN + 1 + 255) / 256), dim3(256), 0, stream,
                           ptr, next, bsum, nN, nE);
        unsigned int nChunks = (nE + EPB - 1) / EPB;
        hipLaunchKernelGGL(scatter_cols_b, dim3(nChunks * 8), dim3(256), 0, stream,
                           row, col, next, colS, nE, W);
    }

    // ---- idx inversion + fused bf16 init ----
    (void)hipMemsetAsync(inext, 0, (size_t)nN * sizeof(int), stream);
    hipLaunchKernelGGL(hist_keys, dim3(gNode), dim3(256), 0, stream, idx, inext, nN);
    hipLaunchKernelGGL(scan_blocks, dim3(NB), dim3(256), 0, stream, inext, iptr, ibsum, nN);
    hipLaunchKernelGGL(scan_bsums, dim3(1), dim3(1024), 0, stream, ibsum, NB);
    hipLaunchKernelGGL(add_offsets, dim3((nN + 1 + 255) / 256), dim3(256), 0, stream,
                       iptr, inext, ibsum, nN, nN);
    hipLaunchKernelGGL(scatter_iota, dim3(gNode), dim3(256), 0, stream,
                       idx, inext, idxS, nN);

    unsigned int gI = (unsigned int)((((size_t)nN + 1) / 2 * 64 + 255) / 256);
    hipLaunchKernelGGL(init_plus_gather_bf, dim3(gI), dim3(256), 0, stream,
                       iptr, idxS, (const float4*)x, (const float4*)x_id, (uint2*)hb0, nN);

    // ---- hops: one wave per node ----
    unsigned int gW = (unsigned int)(((size_t)nN * 64 + 255) / 256);
    hipLaunchKernelGGL(gather_node_bf_bf, dim3(gW), dim3(256), 0, stream,
                       ptr, colS, (const uint4*)hb0, (u32*)hb1, nN);
    hipLaunchKernelGGL(gather_node_bf_bf, dim3(gW), dim3(256), 0, stream,
                       ptr, colS, (const uint4*)hb1, (u32*)hb0, nN);
    hipLaunchKernelGGL(gather_node_bf_f32, dim3(gW), dim3(256), 0, stream,
                       ptr, colS, (const uint4*)hb0, out, nN);
}

// Round 8
// 663.948 us; speedup vs baseline: 1.0956x; 1.0956x over previous
//
#include <hip/hip_runtime.h>

#define D_FEAT 128
typedef unsigned int u32;
typedef u32   u32x4 __attribute__((ext_vector_type(4)));
typedef float f32x4 __attribute__((ext_vector_type(4)));

__device__ __forceinline__ float bflo(u32 w) {
    u32 b = w << 16;
    return __builtin_bit_cast(float, b);
}
__device__ __forceinline__ float bfhi(u32 w) {
    u32 b = w & 0xFFFF0000u;
    return __builtin_bit_cast(float, b);
}
__device__ __forceinline__ u32 f2bf(float f) {
    u32 x = __builtin_bit_cast(u32, f);
    return (x + 0x7FFFu + ((x >> 16) & 1u)) >> 16;
}
__device__ __forceinline__ u32 pack2(float lo, float hi) {
    return f2bf(lo) | (f2bf(hi) << 16);
}

// ---------------- CSR build helpers ----------------

__global__ void hist_keys(const int* __restrict__ key, int* __restrict__ deg, int n) {
    int e = blockIdx.x * blockDim.x + threadIdx.x;
    if (e < n) atomicAdd(&deg[__builtin_nontemporal_load(&key[e])], 1);
}

__global__ void scan_blocks(const int* __restrict__ deg, int* __restrict__ ptrOut,
                            int* __restrict__ bsum, int n) {
    __shared__ int s[256];
    int t = threadIdx.x;
    int i = blockIdx.x * 256 + t;
    int v = (i < n) ? deg[i] : 0;
    s[t] = v;
    __syncthreads();
    for (int off = 1; off < 256; off <<= 1) {
        int add = (t >= off) ? s[t - off] : 0;
        __syncthreads();
        s[t] += add;
        __syncthreads();
    }
    if (i < n) ptrOut[i] = s[t] - v;
    if (t == 255) bsum[blockIdx.x] = s[255];
}

__global__ void scan_bsums(int* __restrict__ bsum, int nb) {
    __shared__ int s[1024];
    int t = threadIdx.x;
    int v = (t < nb) ? bsum[t] : 0;
    s[t] = v;
    __syncthreads();
    for (int off = 1; off < 1024; off <<= 1) {
        int add = (t >= off) ? s[t - off] : 0;
        __syncthreads();
        s[t] += add;
        __syncthreads();
    }
    if (t < nb) bsum[t] = s[t] - v;
}

__global__ void add_offsets(int* __restrict__ ptr, int* __restrict__ next,
                            const int* __restrict__ bsum, int n, int total) {
    int i = blockIdx.x * blockDim.x + threadIdx.x;
    if (i < n) {
        int p = ptr[i] + bsum[i >> 8];
        ptr[i] = p;
        next[i] = p;
    }
    if (i == n) ptr[n] = total;
}

// Bucketed col scatter: bucket = blockIdx&7 (XCD affinity), NT store for placement.
#define EPB 2048
__global__ void scatter_cols_b(const int* __restrict__ row, const int* __restrict__ col,
                               int* __restrict__ next, int* __restrict__ colS,
                               int nE, int W) {
    int bucket = blockIdx.x & 7;
    int chunk  = blockIdx.x >> 3;
    int lo = bucket * W;
    int base = chunk * EPB;
    for (int k = threadIdx.x; k < EPB; k += 256) {
        int e = base + k;
        if (e < nE) {
            int r = __builtin_nontemporal_load(&row[e]);
            if ((unsigned)(r - lo) < (unsigned)W) {
                int c = __builtin_nontemporal_load(&col[e]);
                int pos = atomicAdd(&next[r], 1);
                __builtin_nontemporal_store(c, &colS[pos]);
            }
        }
    }
}

__global__ void scatter_iota(const int* __restrict__ idx, int* __restrict__ inext,
                             int* __restrict__ idxS, int n) {
    int j = blockIdx.x * blockDim.x + threadIdx.x;
    if (j < n) {
        int pos = atomicAdd(&inext[__builtin_nontemporal_load(&idx[j])], 1);
        idxS[pos] = j;
    }
}

// h0(bf16)[n] = x[n] + sum x_id[idxS[...]]  — 2 nodes/wave, 32 lanes/node
__global__ void init_plus_gather_bf(const int* __restrict__ iptr, const int* __restrict__ idxS,
                                    const float4* __restrict__ x, const float4* __restrict__ x_id,
                                    uint2* __restrict__ h, int n) {
    size_t tid = blockIdx.x * (size_t)blockDim.x + threadIdx.x;
    int wv   = (int)(tid >> 6);
    int lane = threadIdx.x & 63;
    int node = wv * 2 + (lane >> 5);
    int q    = lane & 31;
    if (node >= n) return;
    float4 a = x[(size_t)node * 32 + q];
    int e = iptr[node], end = iptr[node + 1];
    for (; e < end; ++e) {
        float4 v = x_id[(size_t)idxS[e] * 32 + q];
        a.x += v.x; a.y += v.y; a.z += v.z; a.w += v.w;
    }
    uint2 w;
    w.x = pack2(a.x, a.y);
    w.y = pack2(a.z, a.w);
    h[(size_t)node * 32 + q] = w;
}

// ---------------- hops: one wave per node, branch-free 32-edge body ----------------
// 8 predicated row-loads in flight per iteration; tail lanes clamp to end-1
// (duplicate loads are L1 hits) and are masked out via 0/1 FMA.

#define CHUNK(K, A0,A1,A2,A3,A4,A5,A6,A7)                                             \
    {                                                                                 \
        int ee = e + 4 * K + g;                                                       \
        float m = (ee < end) ? 1.f : 0.f;                                             \
        if (ee >= end) ee = end - 1;                                                  \
        int c = __builtin_nontemporal_load(&colS[ee]);                                \
        uint4 v = h[(size_t)c * 16 + q];                                              \
        A0 += m * bflo(v.x); A1 += m * bfhi(v.x);                                     \
        A2 += m * bflo(v.y); A3 += m * bfhi(v.y);                                     \
        A4 += m * bflo(v.z); A5 += m * bfhi(v.z);                                     \
        A6 += m * bflo(v.w); A7 += m * bfhi(v.w);                                     \
    }

#define GATHER_BODY                                                                   \
    int wv = (int)((blockIdx.x * (size_t)blockDim.x + threadIdx.x) >> 6);             \
    if (wv >= n) return;                                                              \
    int lane = threadIdx.x & 63;                                                      \
    int g = lane >> 4;                                                                \
    int q = lane & 15;                                                                \
    int beg = ptr[wv], end = ptr[wv + 1];                                             \
    float a0 = 0, a1 = 0, a2 = 0, a3 = 0, a4 = 0, a5 = 0, a6 = 0, a7 = 0;             \
    float b0 = 0, b1 = 0, b2 = 0, b3 = 0, b4 = 0, b5 = 0, b6 = 0, b7 = 0;             \
    for (int e = beg; e < end; e += 32) {                                             \
        CHUNK(0, a0,a1,a2,a3,a4,a5,a6,a7)                                             \
        CHUNK(1, b0,b1,b2,b3,b4,b5,b6,b7)                                             \
        CHUNK(2, a0,a1,a2,a3,a4,a5,a6,a7)                                             \
        CHUNK(3, b0,b1,b2,b3,b4,b5,b6,b7)                                             \
        CHUNK(4, a0,a1,a2,a3,a4,a5,a6,a7)                                             \
        CHUNK(5, b0,b1,b2,b3,b4,b5,b6,b7)                                             \
        CHUNK(6, a0,a1,a2,a3,a4,a5,a6,a7)                                             \
        CHUNK(7, b0,b1,b2,b3,b4,b5,b6,b7)                                             \
    }                                                                                 \
    a0 += b0; a1 += b1; a2 += b2; a3 += b3;                                           \
    a4 += b4; a5 += b5; a6 += b6; a7 += b7;                                           \
    a0 += __shfl_xor(a0, 16, 64); a0 += __shfl_xor(a0, 32, 64);                       \
    a1 += __shfl_xor(a1, 16, 64); a1 += __shfl_xor(a1, 32, 64);                       \
    a2 += __shfl_xor(a2, 16, 64); a2 += __shfl_xor(a2, 32, 64);                       \
    a3 += __shfl_xor(a3, 16, 64); a3 += __shfl_xor(a3, 32, 64);                       \
    a4 += __shfl_xor(a4, 16, 64); a4 += __shfl_xor(a4, 32, 64);                       \
    a5 += __shfl_xor(a5, 16, 64); a5 += __shfl_xor(a5, 32, 64);                       \
    a6 += __shfl_xor(a6, 16, 64); a6 += __shfl_xor(a6, 32, 64);                       \
    a7 += __shfl_xor(a7, 16, 64); a7 += __shfl_xor(a7, 32, 64);

__global__ void gather_node_bf_bf(const int* __restrict__ ptr, const int* __restrict__ colS,
                                  const uint4* __restrict__ h, u32* __restrict__ out, int n) {
    GATHER_BODY
    if (g == 0) {
        u32x4 w;
        w.x = pack2(a0, a1);
        w.y = pack2(a2, a3);
        w.z = pack2(a4, a5);
        w.w = pack2(a6, a7);
        __builtin_nontemporal_store(w, (u32x4*)(out + (size_t)wv * 64 + q * 4));
    }
}

__global__ void gather_node_bf_f32(const int* __restrict__ ptr, const int* __restrict__ colS,
                                   const uint4* __restrict__ h, float* __restrict__ out, int n) {
    GATHER_BODY
    if (g == 0) {
        f32x4 w = {a0, a1, a2, a3};
        __builtin_nontemporal_store(w, (f32x4*)(out + (size_t)wv * 128 + q * 8));
    } else if (g == 1) {
        f32x4 w = {a4, a5, a6, a7};
        __builtin_nontemporal_store(w, (f32x4*)(out + (size_t)wv * 128 + q * 8 + 4));
    }
}

// ---------------- fallback kernels (atomic fp32 path) ----------------

__global__ void init_h0(const float4* __restrict__ x, float4* __restrict__ h, int n4) {
    int i = blockIdx.x * blockDim.x + threadIdx.x;
    if (i < n4) h[i] = x[i];
}

__global__ void scatter_id(const float4* __restrict__ x_id, const int* __restrict__ idx,
                           float* __restrict__ h, int n) {
    int t = blockIdx.x * blockDim.x + threadIdx.x;
    int r = t >> 5;
    int q = t & 31;
    if (r < n) {
        float4 v = x_id[r * 32 + q];
        float* o = h + (size_t)idx[r] * D_FEAT + q * 4;
        atomicAdd(o + 0, v.x);
        atomicAdd(o + 1, v.y);
        atomicAdd(o + 2, v.z);
        atomicAdd(o + 3, v.w);
    }
}

__global__ void edge_scatter(const int* __restrict__ row, const int* __restrict__ col,
                             const float4* __restrict__ h, float* __restrict__ out, int nE) {
    int t = blockIdx.x * blockDim.x + threadIdx.x;
    int e = t >> 5;
    int q = t & 31;
    if (e < nE) {
        float4 v = h[col[e] * 32 + q];
        float* o = out + (size_t)row[e] * D_FEAT + q * 4;
        atomicAdd(o + 0, v.x);
        atomicAdd(o + 1, v.y);
        atomicAdd(o + 2, v.z);
        atomicAdd(o + 3, v.w);
    }
}

extern "C" void kernel_launch(void* const* d_in, const int* in_sizes, int n_in,
                              void* d_out, int out_size, void* d_ws, size_t ws_size,
                              hipStream_t stream) {
    const float* x    = (const float*)d_in[0];
    const float* x_id = (const float*)d_in[1];
    const int*   edge = (const int*)d_in[2];   // [2, nE]: row then col
    const int*   idx  = (const int*)d_in[3];

    int nE = in_sizes[2] / 2;
    int nN = in_sizes[3];
    const int* row = edge;
    const int* col = edge + nE;

    float* out = (float*)d_out;
    size_t hbytes  = (size_t)nN * D_FEAT * sizeof(float);
    size_t hbbytes = (size_t)nN * D_FEAT * 2;
    int NB = (nN + 255) / 256;
    int W  = (nN + 7) / 8;

    // ---- workspace layout ----
    char* base = (char*)d_ws;
    uint4* hb0  = (uint4*)base;                            // hbbytes
    uint4* hb1  = (uint4*)(base + hbbytes);                // hbbytes
    int*   ptr   = (int*)(base + 2 * hbbytes);             // nN+1
    int*   next  = ptr + (nN + 1);                         // nN
    int*   bsum  = next + nN;                              // NB (padded)
    int*   colS  = bsum + ((NB + 3) & ~3);                 // nE
    int*   iptr  = colS + nE;                              // nN+1
    int*   inext = iptr + (nN + 1);                        // nN
    int*   ibsum = inext + nN;                             // NB (padded)
    int*   idxS  = ibsum + ((NB + 3) & ~3);                // nN
    size_t needBF = 2 * hbbytes + sizeof(int) *
        ((size_t)(nN + 1) * 2 + (size_t)nN * 2 + 2 * ((NB + 3) & ~3) + nE + nN);

    int n4 = nN * D_FEAT / 4;
    unsigned int gEdge = (nE + 255) / 256;
    unsigned int gNode = (nN + 255) / 256;

    if (needBF > ws_size || NB > 1024) {
        float* h = (float*)d_ws;
        (void)hipMemsetAsync(out, 0, hbytes, stream);
        hipLaunchKernelGGL(init_h0, dim3((n4 + 255) / 256), dim3(256), 0, stream,
                           (const float4*)x, (float4*)h, n4);
        hipLaunchKernelGGL(scatter_id, dim3((nN * 32 + 255) / 256), dim3(256), 0, stream,
                           (const float4*)x_id, idx, h, nN);
        long long totE = (long long)nE * 32;
        unsigned int gE = (unsigned int)((totE + 255) / 256);
        hipLaunchKernelGGL(edge_scatter, dim3(gE), dim3(256), 0, stream,
                           row, col, (const float4*)h, out, nE);
        (void)hipMemsetAsync(h, 0, hbytes, stream);
        hipLaunchKernelGGL(edge_scatter, dim3(gE), dim3(256), 0, stream,
                           row, col, (const float4*)out, h, nE);
        (void)hipMemsetAsync(out, 0, hbytes, stream);
        hipLaunchKernelGGL(edge_scatter, dim3(gE), dim3(256), 0, stream,
                           row, col, (const float4*)h, out, nE);
        return;
    }

    // ---- edge CSR: hist -> scan -> bucketed NT scatter ----
    (void)hipMemsetAsync(next, 0, (size_t)nN * sizeof(int), stream);
    hipLaunchKernelGGL(hist_keys, dim3(gEdge), dim3(256), 0, stream, row, next, nE);
    hipLaunchKernelGGL(scan_blocks, dim3(NB), dim3(256), 0, stream, next, ptr, bsum, nN);
    hipLaunchKernelGGL(scan_bsums, dim3(1), dim3(1024), 0, stream, bsum, NB);
    hipLaunchKernelGGL(add_offsets, dim3((nN + 1 + 255) / 256), dim3(256), 0, stream,
                       ptr, next, bsum, nN, nE);
    {
        unsigned int nChunks = (nE + EPB - 1) / EPB;
        hipLaunchKernelGGL(scatter_cols_b, dim3(nChunks * 8), dim3(256), 0, stream,
                           row, col, next, colS, nE, W);
    }

    // ---- idx inversion + fused bf16 init ----
    (void)hipMemsetAsync(inext, 0, (size_t)nN * sizeof(int), stream);
    hipLaunchKernelGGL(hist_keys, dim3(gNode), dim3(256), 0, stream, idx, inext, nN);
    hipLaunchKernelGGL(scan_blocks, dim3(NB), dim3(256), 0, stream, inext, iptr, ibsum, nN);
    hipLaunchKernelGGL(scan_bsums, dim3(1), dim3(1024), 0, stream, ibsum, NB);
    hipLaunchKernelGGL(add_offsets, dim3((nN + 1 + 255) / 256), dim3(256), 0, stream,
                       iptr, inext, ibsum, nN, nN);
    hipLaunchKernelGGL(scatter_iota, dim3(gNode), dim3(256), 0, stream,
                       idx, inext, idxS, nN);

    unsigned int gI = (unsigned int)((((size_t)nN + 1) / 2 * 64 + 255) / 256);
    hipLaunchKernelGGL(init_plus_gather_bf, dim3(gI), dim3(256), 0, stream,
                       iptr, idxS, (const float4*)x, (const float4*)x_id, (uint2*)hb0, nN);

    // ---- hops: one wave per node ----
    unsigned int gW = (unsigned int)(((size_t)nN * 64 + 255) / 256);
    hipLaunchKernelGGL(gather_node_bf_bf, dim3(gW), dim3(256), 0, stream,
                       ptr, colS, (const uint4*)hb0, (u32*)hb1, nN);
    hipLaunchKernelGGL(gather_node_bf_bf, dim3(gW), dim3(256), 0, stream,
                       ptr, colS, (const uint4*)hb1, (u32*)hb0, nN);
    hipLaunchKernelGGL(gather_node_bf_f32, dim3(gW), dim3(256), 0, stream,
                       ptr, colS, (const uint4*)hb0, out, nN);
}